// Round 17
// baseline (793.050 us; speedup 1.0000x reference)
//
#include <hip/hip_runtime.h>
#include <hip/hip_bf16.h>
#include <stdint.h>

#define M_TOTAL 16384
#define N_TOTAL 4096
#define K_TOTAL 4096
#define NSTEP (K_TOTAL / 64)   // 64 K-steps of 64
#define NT32 (K_TOTAL / 32)

typedef __attribute__((ext_vector_type(8))) short bf16x8;
typedef __attribute__((ext_vector_type(4))) float f32x4;

__device__ __forceinline__ void gload_lds16(const void* g, void* l) {
    __builtin_amdgcn_global_load_lds(
        (const __attribute__((address_space(1))) uint32_t*)g,
        (__attribute__((address_space(3))) uint32_t*)l, 16, 0, 0);
}

// ---------------------------------------------------------------------------
// Kernel 0: X f32 -> bf16.
// ---------------------------------------------------------------------------
__global__ __launch_bounds__(256) void k_convX(const float* __restrict__ X,
                                               __hip_bfloat16* __restrict__ Xb) {
    size_t t = (size_t)blockIdx.x * 256 + threadIdx.x;
    const float* p = X + t * 8;
    float4 a = *(const float4*)p;
    float4 b = *(const float4*)(p + 4);
    __hip_bfloat162 o[4] = {
        __float22bfloat162_rn(make_float2(a.x, a.y)),
        __float22bfloat162_rn(make_float2(a.z, a.w)),
        __float22bfloat162_rn(make_float2(b.x, b.y)),
        __float22bfloat162_rn(make_float2(b.z, b.w))};
    *(int4*)(Xb + t * 8) = *(int4*)&o[0];
}

// ---------------------------------------------------------------------------
// Kernel 1: packed int4 -> bf16 W[N][K].
// ---------------------------------------------------------------------------
__global__ __launch_bounds__(256) void k_dequant(const int* __restrict__ pw,
                                                 const float* __restrict__ sc,
                                                 __hip_bfloat16* __restrict__ W) {
    int t = blockIdx.x * 256 + threadIdx.x;
    int row = t >> 8;
    int w0 = (t & 255) << 3;
    const int* p = pw + (size_t)row * 2048 + w0;
    int4 q0 = *(const int4*)p;
    int4 q1 = *(const int4*)(p + 4);
    float s = sc[row * 128 + (w0 >> 4)];
    float ns8 = -8.0f * s;
    int w[8] = {q0.x, q0.y, q0.z, q0.w, q1.x, q1.y, q1.z, q1.w};
    __hip_bfloat162 o[8];
#pragma unroll
    for (int i = 0; i < 8; ++i) {
        float lo = fmaf((float)(w[i] & 15), s, ns8);
        float hi = fmaf((float)(w[i] >> 4), s, ns8);
        o[i] = __float22bfloat162_rn(make_float2(lo, hi));
    }
    __hip_bfloat16* dst = W + (size_t)row * 4096 + w0 * 2;
    *(int4*)dst = *(int4*)&o[0];
    *(int4*)(dst + 8) = *(int4*)&o[4];
}

// ---------------------------------------------------------------------------
// Kernel 2 (tier A): r16 (dual-barrier 8-phase, full-XOR layout, 0-conflict)
// + LAG-1 READS via consumption-region LDS packing + publish-at-phase-start.
//
// LDS regions per buf (16KB each = 2 gloads): A_lo (global rows {0-63,
// 128-191}, region-row = g*64+r), A_hi ({64-127,192-255}), B01 (rows
// q*64+0..31, region-row = q*32+r), B23 (q*64+32..63).
// Wave reads: A region-row = wm*64+(rf&3)*16+l15; B = wn*32+(cf&1)*16+l15.
// XOR key = region-row&7 = l15&7 both sides (r16-verified 0-conflict).
//
// Phases (step s in buf0, s+1 in buf1; Q1=AL*B01, Q2=AL*B23, Q3=AH*B01,
// Q4=AH*B23; every MFMA's operands read >=1 phase earlier):
//  P1: rd B23(s);           st B23(s+1);   Q1(s)
//  P2: rd A_hi(s);          st A_hi(s+1);  Q2(s)
//  P3:                      st A_lo(s+2);  Q3(s)
//  P4: VMW(2)+BAR [publish tile s+1]; rd A_lo,B01(s+1); st B01(s+2); Q4(s)
//  P5: rd B23(s+1);         st B23(s+2);   Q1(s+1)
//  P6: rd A_hi(s+1);        st A_hi(s+2);  Q2(s+1)
//  P7:                      st A_lo(s+3);  Q3(s+1)
//  P8: VMW(2)+BAR [publish tile s+2]; rd A_lo,B01(s+2); st B01(s+3); Q4(s+1)
// Stage safety: each region staged >=1 exit-BAR after its consuming MFMA
// (audited per-region). vmcnt ledger: 10 outstanding at P4/P8 -> VMW(2)
// drains exactly the tile being published. Last iter: no stages beyond
// tile s+1, VMW(0) at P4, P8 reads skipped.
// ---------------------------------------------------------------------------
__global__ __launch_bounds__(512, 2) void k_gemm17(const __hip_bfloat16* __restrict__ Xb,
                                                   const __hip_bfloat16* __restrict__ Wb,
                                                   float* __restrict__ out) {
    __shared__ __align__(16) short L[2][4][8192];  // [buf][AL,AH,B01,B23][16KB]

    int bid = blockIdx.x;
    int swz = (bid & 7) * 128 + (bid >> 3);        // XCD-bijective (1024%8==0)
    int bn = swz & 15, bm = swz >> 4;
    int m0 = bm * 256, n0 = bn * 256;
    int t = threadIdx.x, lane = t & 63, wv = t >> 6;
    int wm = wv >> 2, wn = wv & 3;

    // staging source rows (pre-swizzled k): sko = (t&7)*8 ^ ((t>>3)&7)*8
    int sko = ((t & 7) * 8) ^ (((t >> 3) & 7) * 8);
    int arow0 = t >> 3;                                    // A gl0 row
    int brow0 = ((t >> 8) & 1) * 64 + ((t >> 3) & 31);     // B01 gl0 row
    const __hip_bfloat16* pA = Xb + (size_t)(m0 + arow0) * K_TOTAL + sko;
    const __hip_bfloat16* pB = Wb + (size_t)(n0 + brow0) * K_TOTAL + sko;

    auto ST_AL = [&](int T) { int b = T & 1;
        gload_lds16(pA + T * 64, &L[b][0][t * 8]);
        gload_lds16(pA + (size_t)128 * K_TOTAL + T * 64, &L[b][0][4096 + t * 8]); };
    auto ST_AH = [&](int T) { int b = T & 1;
        gload_lds16(pA + (size_t)64 * K_TOTAL + T * 64, &L[b][1][t * 8]);
        gload_lds16(pA + (size_t)192 * K_TOTAL + T * 64, &L[b][1][4096 + t * 8]); };
    auto ST_B01 = [&](int T) { int b = T & 1;
        gload_lds16(pB + T * 64, &L[b][2][t * 8]);
        gload_lds16(pB + (size_t)128 * K_TOTAL + T * 64, &L[b][2][4096 + t * 8]); };
    auto ST_B23 = [&](int T) { int b = T & 1;
        gload_lds16(pB + (size_t)32 * K_TOTAL + T * 64, &L[b][3][t * 8]);
        gload_lds16(pB + (size_t)160 * K_TOTAL + T * 64, &L[b][3][4096 + t * 8]); };

    // read offsets: kx = kb ^ ((l15&7)<<3); kk=1 -> addr ^ 32
    const int l15 = lane & 15;
    const int kx = ((lane >> 4) * 8) ^ ((l15 & 7) << 3);
    const int AOFF = wm * 4096 + l15 * 64 + kx;
    const int BOFF = wn * 2048 + l15 * 64 + kx;

    f32x4 acc[8][4];
#pragma unroll
    for (int f = 0; f < 8; ++f)
#pragma unroll
        for (int j = 0; j < 4; ++j) acc[f][j] = (f32x4)(0.0f);

    bf16x8 AL[8], AH[8], B1r[4], B2r[4];

#define BAR __builtin_amdgcn_s_barrier()
#define PRI(x) __builtin_amdgcn_s_setprio(x)
#define SB0 __builtin_amdgcn_sched_barrier(0)
#define VMW(n) { asm volatile("s_waitcnt vmcnt(" #n ")" ::: "memory"); SB0; }

#define RDAL(b) { const short* Lp = &L[b][0][0]; _Pragma("unroll") \
    for (int rf = 0; rf < 4; ++rf) { int a0 = AOFF + rf * 1024; \
        AL[rf * 2] = *(const bf16x8*)&Lp[a0]; \
        AL[rf * 2 + 1] = *(const bf16x8*)&Lp[a0 ^ 32]; } }
#define RDAH(b) { const short* Lp = &L[b][1][0]; _Pragma("unroll") \
    for (int rf = 0; rf < 4; ++rf) { int a0 = AOFF + rf * 1024; \
        AH[rf * 2] = *(const bf16x8*)&Lp[a0]; \
        AH[rf * 2 + 1] = *(const bf16x8*)&Lp[a0 ^ 32]; } }
#define RDB01(b) { const short* Lp = &L[b][2][0]; _Pragma("unroll") \
    for (int cf = 0; cf < 2; ++cf) { int a0 = BOFF + cf * 1024; \
        B1r[cf * 2] = *(const bf16x8*)&Lp[a0]; \
        B1r[cf * 2 + 1] = *(const bf16x8*)&Lp[a0 ^ 32]; } }
#define RDB23(b) { const short* Lp = &L[b][3][0]; _Pragma("unroll") \
    for (int cf = 0; cf < 2; ++cf) { int a0 = BOFF + cf * 1024; \
        B2r[cf * 2] = *(const bf16x8*)&Lp[a0]; \
        B2r[cf * 2 + 1] = *(const bf16x8*)&Lp[a0 ^ 32]; } }
#define QMM(rb, cb, Av, Bv) { _Pragma("unroll") for (int kk = 0; kk < 2; ++kk) \
    _Pragma("unroll") for (int rf = 0; rf < 4; ++rf) \
    _Pragma("unroll") for (int cf = 0; cf < 2; ++cf) \
        acc[(rb) + rf][(cb) + cf] = __builtin_amdgcn_mfma_f32_16x16x32_bf16( \
            Av[rf * 2 + kk], Bv[cf * 2 + kk], acc[(rb) + rf][(cb) + cf], 0, 0, 0); }

    // ---- prologue: tile0 all regions, tile1 A_lo+B01; drain tile0; prime ----
    ST_AL(0); ST_AH(0); ST_B01(0); ST_B23(0);
    ST_AL(1); ST_B01(1);
    VMW(4);
    BAR; SB0;
    RDAL(0) RDB01(0)

    for (int i = 0; i < NSTEP / 2; ++i) {
        const int s = 2 * i;
        const bool last = (i == NSTEP / 2 - 1);
        // P1
        RDB23(0)
        ST_B23(s + 1);
        BAR; PRI(1); QMM(0, 0, AL, B1r) PRI(0); BAR;
        // P2
        RDAH(0)
        ST_AH(s + 1);
        BAR; PRI(1); QMM(0, 2, AL, B2r) PRI(0); BAR;
        // P3
        if (!last) ST_AL(s + 2);
        BAR; PRI(1); QMM(4, 0, AH, B1r) PRI(0); BAR;
        // P4 (publish tile s+1)
        if (last) { VMW(0) } else { VMW(2) }
        BAR; SB0;
        RDAL(1) RDB01(1)
        if (!last) ST_B01(s + 2);
        BAR; PRI(1); QMM(4, 2, AH, B2r) PRI(0); BAR;
        // P5
        RDB23(1)
        if (!last) ST_B23(s + 2);
        BAR; PRI(1); QMM(0, 0, AL, B1r) PRI(0); BAR;
        // P6
        RDAH(1)
        if (!last) ST_AH(s + 2);
        BAR; PRI(1); QMM(0, 2, AL, B2r) PRI(0); BAR;
        // P7
        if (!last) ST_AL(s + 3);
        BAR; PRI(1); QMM(4, 0, AH, B1r) PRI(0); BAR;
        // P8 (publish tile s+2)
        if (!last) {
            VMW(2)
            BAR; SB0;
            RDAL(0) RDB01(0)
            ST_B01(s + 3);
        }
        BAR; PRI(1); QMM(4, 2, AH, B2r) PRI(0); BAR;
    }
#undef RDAL
#undef RDAH
#undef RDB01
#undef RDB23
#undef QMM
#undef BAR
#undef PRI
#undef SB0
#undef VMW

    // ---- epilogue: C/D layout col=lane&15, row=(lane>>4)*4+reg ----
    int col0 = n0 + wn * 64 + l15;
    int row0 = m0 + wm * 128 + (lane >> 4) * 4;
#pragma unroll
    for (int f = 0; f < 8; ++f)
#pragma unroll
        for (int j = 0; j < 4; ++j) {
            f32x4 v = acc[f][j];
            int r = row0 + f * 16;
            int c = col0 + j * 16;
#pragma unroll
            for (int q = 0; q < 4; ++q)
                out[(size_t)(r + q) * N_TOTAL + c] = v[q];
        }
}

// ---------------------------------------------------------------------------
// Tier B: m97-structure GEMM, A reg-staged from f32 X (round-5 verified).
// ---------------------------------------------------------------------------
__global__ __launch_bounds__(256) void k_gemm2b(const float* __restrict__ X,
                                                const __hip_bfloat16* __restrict__ Wb,
                                                float* __restrict__ out) {
    __shared__ __align__(16) short As[128 * 32];
    __shared__ __align__(16) short Bs[128 * 32];
    int bid = blockIdx.x;
    int swz = (bid & 7) * 512 + (bid >> 3);
    int bn = swz & 31, bm = swz >> 5;
    int m0 = bm * 128, n0 = bn * 128;
    int t = threadIdx.x, lane = t & 63, wv = t >> 6;
    int wr = wv >> 1, wc = wv & 1;
    f32x4 acc[4][4];
#pragma unroll
    for (int i = 0; i < 4; ++i)
#pragma unroll
        for (int j = 0; j < 4; ++j) acc[i][j] = (f32x4)(0.0f);
    int arow = t >> 2, acol = (t & 3) * 8;
    const float* Agf0 = X + (size_t)(m0 + arow) * K_TOTAL + acol;
    const float* Agf1 = Agf0 + (size_t)64 * K_TOTAL;
    const __hip_bfloat16* Bg0 = Wb + (size_t)(n0 + arow) * K_TOTAL + acol;
    const __hip_bfloat16* Bg1 = Bg0 + (size_t)64 * K_TOTAL;
    float4 xa0 = *(const float4*)(Agf0), xa1 = *(const float4*)(Agf0 + 4);
    float4 xb0 = *(const float4*)(Agf1), xb1 = *(const float4*)(Agf1 + 4);
    for (int kt = 0; kt < NT32; ++kt) {
        if (kt) __syncthreads();
        __hip_bfloat162 oa[4] = {
            __float22bfloat162_rn(make_float2(xa0.x, xa0.y)),
            __float22bfloat162_rn(make_float2(xa0.z, xa0.w)),
            __float22bfloat162_rn(make_float2(xa1.x, xa1.y)),
            __float22bfloat162_rn(make_float2(xa1.z, xa1.w))};
        __hip_bfloat162 ob[4] = {
            __float22bfloat162_rn(make_float2(xb0.x, xb0.y)),
            __float22bfloat162_rn(make_float2(xb0.z, xb0.w)),
            __float22bfloat162_rn(make_float2(xb1.x, xb1.y)),
            __float22bfloat162_rn(make_float2(xb1.z, xb1.w))};
        *(int4*)&As[t * 8] = *(int4*)&oa[0];
        *(int4*)&As[2048 + t * 8] = *(int4*)&ob[0];
        gload_lds16(Bg0 + kt * 32, &Bs[t * 8]);
        gload_lds16(Bg1 + kt * 32, &Bs[2048 + t * 8]);
        __syncthreads();
        if (kt < NT32 - 1) {
            int ko = (kt + 1) * 32;
            xa0 = *(const float4*)(Agf0 + ko);
            xa1 = *(const float4*)(Agf0 + ko + 4);
            xb0 = *(const float4*)(Agf1 + ko);
            xb1 = *(const float4*)(Agf1 + ko + 4);
        }
        bf16x8 a[4], b[4];
        int ro = (lane & 15) * 32 + (lane >> 4) * 8;
#pragma unroll
        for (int i = 0; i < 4; ++i)
            a[i] = *(const bf16x8*)&As[(wr * 64 + i * 16) * 32 + ro];
#pragma unroll
        for (int j = 0; j < 4; ++j)
            b[j] = *(const bf16x8*)&Bs[(wc * 64 + j * 16) * 32 + ro];
#pragma unroll
        for (int i = 0; i < 4; ++i)
#pragma unroll
            for (int j = 0; j < 4; ++j)
                acc[i][j] = __builtin_amdgcn_mfma_f32_16x16x32_bf16(a[i], b[j], acc[i][j], 0, 0, 0);
    }
    int col0 = n0 + wc * 64 + (lane & 15);
    int row0 = m0 + wr * 64 + (lane >> 4) * 4;
#pragma unroll
    for (int i = 0; i < 4; ++i)
#pragma unroll
        for (int j = 0; j < 4; ++j) {
            f32x4 v = acc[i][j];
            int r = row0 + i * 16, c = col0 + j * 16;
#pragma unroll
            for (int q = 0; q < 4; ++q)
                out[(size_t)(r + q) * N_TOTAL + c] = v[q];
        }
}

extern "C" void kernel_launch(void* const* d_in, const int* in_sizes, int n_in,
                              void* d_out, int out_size, void* d_ws, size_t ws_size,
                              hipStream_t stream) {
    const float* X = (const float*)d_in[0];
    const int* PW = (const int*)d_in[1];
    const float* SC = (const float*)d_in[2];
    float* OUT = (float*)d_out;

    const size_t needW = (size_t)N_TOTAL * K_TOTAL * 2;            // 33.5 MB
    const size_t needX = needW + (size_t)M_TOTAL * K_TOTAL * 2;    // +134 MB

    if (ws_size >= needX) {
        __hip_bfloat16* Wb = (__hip_bfloat16*)d_ws;
        __hip_bfloat16* Xb = (__hip_bfloat16*)((char*)d_ws + needW);
        k_convX<<<dim3(32768), dim3(256), 0, stream>>>(X, Xb);
        k_dequant<<<dim3(4096), dim3(256), 0, stream>>>(PW, SC, Wb);
        k_gemm17<<<dim3((M_TOTAL / 256) * (N_TOTAL / 256)), dim3(512), 0, stream>>>(Xb, Wb, OUT);
    } else if (ws_size >= needW) {
        __hip_bfloat16* Wb = (__hip_bfloat16*)d_ws;
        k_dequant<<<dim3(4096), dim3(256), 0, stream>>>(PW, SC, Wb);
        k_gemm2b<<<dim3((M_TOTAL / 128) * (N_TOTAL / 128)), dim3(256), 0, stream>>>(X, Wb, OUT);
    }
}

// Round 18
// 531.948 us; speedup vs baseline: 1.4908x; 1.4908x over previous
//
#include <hip/hip_runtime.h>
#include <hip/hip_bf16.h>
#include <stdint.h>

#define M_TOTAL 16384
#define N_TOTAL 4096
#define K_TOTAL 4096
#define NSTEP (K_TOTAL / 64)   // 64 K-steps of 64
#define NT32 (K_TOTAL / 32)

typedef __attribute__((ext_vector_type(8))) short bf16x8;
typedef __attribute__((ext_vector_type(4))) float f32x4;

__device__ __forceinline__ void gload_lds16(const void* g, void* l) {
    __builtin_amdgcn_global_load_lds(
        (const __attribute__((address_space(1))) uint32_t*)g,
        (__attribute__((address_space(3))) uint32_t*)l, 16, 0, 0);
}

// ---------------------------------------------------------------------------
// Kernel 0: X f32 -> bf16.
// ---------------------------------------------------------------------------
__global__ __launch_bounds__(256) void k_convX(const float* __restrict__ X,
                                               __hip_bfloat16* __restrict__ Xb) {
    size_t t = (size_t)blockIdx.x * 256 + threadIdx.x;
    const float* p = X + t * 8;
    float4 a = *(const float4*)p;
    float4 b = *(const float4*)(p + 4);
    __hip_bfloat162 o[4] = {
        __float22bfloat162_rn(make_float2(a.x, a.y)),
        __float22bfloat162_rn(make_float2(a.z, a.w)),
        __float22bfloat162_rn(make_float2(b.x, b.y)),
        __float22bfloat162_rn(make_float2(b.z, b.w))};
    *(int4*)(Xb + t * 8) = *(int4*)&o[0];
}

// ---------------------------------------------------------------------------
// Kernel 1: packed int4 -> bf16 W[N][K].
// ---------------------------------------------------------------------------
__global__ __launch_bounds__(256) void k_dequant(const int* __restrict__ pw,
                                                 const float* __restrict__ sc,
                                                 __hip_bfloat16* __restrict__ W) {
    int t = blockIdx.x * 256 + threadIdx.x;
    int row = t >> 8;
    int w0 = (t & 255) << 3;
    const int* p = pw + (size_t)row * 2048 + w0;
    int4 q0 = *(const int4*)p;
    int4 q1 = *(const int4*)(p + 4);
    float s = sc[row * 128 + (w0 >> 4)];
    float ns8 = -8.0f * s;
    int w[8] = {q0.x, q0.y, q0.z, q0.w, q1.x, q1.y, q1.z, q1.w};
    __hip_bfloat162 o[8];
#pragma unroll
    for (int i = 0; i < 8; ++i) {
        float lo = fmaf((float)(w[i] & 15), s, ns8);
        float hi = fmaf((float)(w[i] >> 4), s, ns8);
        o[i] = __float22bfloat162_rn(make_float2(lo, hi));
    }
    __hip_bfloat16* dst = W + (size_t)row * 4096 + w0 * 2;
    *(int4*)dst = *(int4*)&o[0];
    *(int4*)(dst + 8) = *(int4*)&o[4];
}

// ---------------------------------------------------------------------------
// Kernel 2 (tier A): ONE-VARIABLE experiment vs r16 — barrier structure.
// = r9's exact single-barrier-per-phase schedule (race-audited: stage at
// phase p issues after BAR(p-1) => reads from phases <= p-2 consumed; each
// stage slot targets a half-buffer whose last reads are >= 2 phases old)
// + r16's verified LDS layout (row-major [128][64] half-tiles, full 3-bit
// XOR k' = k ^ ((row&7)<<3), pre-swizzled global source, 0-conflict).
// Register cost identical to r16 (no extra frag sets -> no r17 spill).
//
// r9 stage rotation: p1:B(s+1)h1->b1, p2:A(s+1)h0->b1, p3:A(s+1)h1->b1,
// p4:B(s+2)h0->b0 +VMW(2), p5:B(s+2)h1->b0, p6:A(s+2)h0->b0,
// p7:A(s+2)h1->b0, p8:B(s+3)h0->b1 +VMW(2). Prologue: b0 full + B(1)h0,
// VMW(2). Never vmcnt(0) except tail.
// ---------------------------------------------------------------------------
__global__ __launch_bounds__(512, 2) void k_gemm18(const __hip_bfloat16* __restrict__ Xb,
                                                   const __hip_bfloat16* __restrict__ Wb,
                                                   float* __restrict__ out) {
    __shared__ __align__(16) short L[2][2][2][8192];  // [buf][A/B][half][16KB]

    int bid = blockIdx.x;
    int swz = (bid & 7) * 128 + (bid >> 3);           // XCD-bijective (1024%8==0)
    int bn = swz & 15, bm = swz >> 4;
    int m0 = bm * 256, n0 = bn * 256;
    int t = threadIdx.x, lane = t & 63, wv = t >> 6;
    int wm = wv >> 2, wn = wv & 3, wnh = wn >> 1;

    // staging source (pre-swizzled, 3-bit XOR): row g*64+(t>>3),
    // k = (t&7)*8 ^ ((t>>3)&7)*8
    int srow = t >> 3;
    int sko = ((t & 7) * 8) ^ (((t >> 3) & 7) * 8);
    const __hip_bfloat16* gA = Xb + (size_t)(m0 + srow) * K_TOTAL + sko;
    const __hip_bfloat16* gB = Wb + (size_t)(n0 + srow) * K_TOTAL + sko;

    auto stA = [&](int b, int h, int s_) {
        gload_lds16(gA + (size_t)(h * 128) * K_TOTAL + s_ * 64, &L[b][0][h][t * 8]);
        gload_lds16(gA + (size_t)(h * 128 + 64) * K_TOTAL + s_ * 64, &L[b][0][h][4096 + t * 8]);
    };
    auto stB = [&](int b, int h, int s_) {
        gload_lds16(gB + (size_t)(h * 128) * K_TOTAL + s_ * 64, &L[b][1][h][t * 8]);
        gload_lds16(gB + (size_t)(h * 128 + 64) * K_TOTAL + s_ * 64, &L[b][1][h][4096 + t * 8]);
    };

    // frag-read lane constants (3-bit XOR, r16-verified)
    const int l15 = lane & 15;
    const int kb = (lane >> 4) * 8;
    const int kx = kb ^ ((l15 & 7) << 3);
    const int roff = l15 * 64 + kx;
    const int roff2 = roff ^ 32;
    const int bco = (wn & 1) * 4096;

    f32x4 acc[8][4];
#pragma unroll
    for (int f = 0; f < 8; ++f)
#pragma unroll
        for (int j = 0; j < 4; ++j) acc[f][j] = (f32x4)(0.0f);

    bf16x8 Af[8], Bq01[4], Bq23[4];

#define RD_A(rfb) { _Pragma("unroll") for (int rf = 0; rf < 4; ++rf) { \
        Af[rf * 2]     = *(const bf16x8*)&LA[((rfb) + rf) * 1024 + roff]; \
        Af[rf * 2 + 1] = *(const bf16x8*)&LA[((rfb) + rf) * 1024 + roff2]; } }
#define RD_B(dst, cfb) { _Pragma("unroll") for (int cf = 0; cf < 2; ++cf) { \
        dst[cf * 2]     = *(const bf16x8*)&LB[bco + ((cfb) + cf) * 1024 + roff]; \
        dst[cf * 2 + 1] = *(const bf16x8*)&LB[bco + ((cfb) + cf) * 1024 + roff2]; } }
#define MM16(rfb, Bv, cfb) { _Pragma("unroll") for (int kk = 0; kk < 2; ++kk) \
        _Pragma("unroll") for (int rf = 0; rf < 4; ++rf) \
        _Pragma("unroll") for (int cf = 0; cf < 2; ++cf) \
            acc[(rfb) + rf][(cfb) + cf] = __builtin_amdgcn_mfma_f32_16x16x32_bf16( \
                Af[rf * 2 + kk], Bv[cf * 2 + kk], acc[(rfb) + rf][(cfb) + cf], 0, 0, 0); }
#define BAR __builtin_amdgcn_s_barrier()
#define PRI(x) __builtin_amdgcn_s_setprio(x)
#define VMW(n) { asm volatile("s_waitcnt vmcnt(" #n ")" ::: "memory"); \
                 __builtin_amdgcn_sched_barrier(0); }

    // ---- prologue (r9-identical): b0 full (B then A), B(1)h0; VMW(2) ----
    stB(0, 0, 0); stB(0, 1, 0);
    stA(0, 0, 0); stA(0, 1, 0);
    stB(1, 0, 1);
    VMW(2);
    BAR;

    for (int i = 0; i < NSTEP / 2; ++i) {
        const int s = 2 * i;
        const bool g2 = (s + 2 < NSTEP);
        const bool g3 = (s + 3 < NSTEP);
        // ======== K-step s (buf 0) ========
        {
            const short* LA = &L[0][0][wm][0];
            const short* LB = &L[0][1][wnh][0];
            // p1
            RD_A(0) RD_B(Bq01, 0)
            stB(1, 1, s + 1);
            BAR; PRI(1); MM16(0, Bq01, 0) PRI(0);
            // p2
            RD_B(Bq23, 2)
            stA(1, 0, s + 1);
            BAR; PRI(1); MM16(0, Bq23, 2) PRI(0);
            // p3
            RD_A(4)
            stA(1, 1, s + 1);
            BAR; PRI(1); MM16(4, Bq01, 0) PRI(0);
            // p4
            if (g2) stB(0, 0, s + 2);
            BAR; PRI(1); MM16(4, Bq23, 2) PRI(0);
            if (g2) { VMW(2) } else { VMW(0) }
            BAR;
        }
        // ======== K-step s+1 (buf 1) ========
        {
            const short* LA = &L[1][0][wm][0];
            const short* LB = &L[1][1][wnh][0];
            // p5
            RD_A(0) RD_B(Bq01, 0)
            if (g2) stB(0, 1, s + 2);
            BAR; PRI(1); MM16(0, Bq01, 0) PRI(0);
            // p6
            RD_B(Bq23, 2)
            if (g2) stA(0, 0, s + 2);
            BAR; PRI(1); MM16(0, Bq23, 2) PRI(0);
            // p7
            RD_A(4)
            if (g2) stA(0, 1, s + 2);
            BAR; PRI(1); MM16(4, Bq01, 0) PRI(0);
            // p8
            if (g3) stB(1, 0, s + 3);
            BAR; PRI(1); MM16(4, Bq23, 2) PRI(0);
            if (i < NSTEP / 2 - 1) {
                if (g3) { VMW(2) } else { VMW(0) }
                BAR;
            }
        }
    }
#undef RD_A
#undef RD_B
#undef MM16
#undef BAR
#undef PRI
#undef VMW

    // ---- epilogue: C/D layout col=lane&15, row=(lane>>4)*4+reg ----
    int col0 = n0 + wn * 64 + l15;
    int row0 = m0 + wm * 128 + (lane >> 4) * 4;
#pragma unroll
    for (int f = 0; f < 8; ++f)
#pragma unroll
        for (int j = 0; j < 4; ++j) {
            f32x4 v = acc[f][j];
            int r = row0 + f * 16;
            int c = col0 + j * 16;
#pragma unroll
            for (int q = 0; q < 4; ++q)
                out[(size_t)(r + q) * N_TOTAL + c] = v[q];
        }
}

// ---------------------------------------------------------------------------
// Tier B: m97-structure GEMM, A reg-staged from f32 X (round-5 verified).
// ---------------------------------------------------------------------------
__global__ __launch_bounds__(256) void k_gemm2b(const float* __restrict__ X,
                                                const __hip_bfloat16* __restrict__ Wb,
                                                float* __restrict__ out) {
    __shared__ __align__(16) short As[128 * 32];
    __shared__ __align__(16) short Bs[128 * 32];
    int bid = blockIdx.x;
    int swz = (bid & 7) * 512 + (bid >> 3);
    int bn = swz & 31, bm = swz >> 5;
    int m0 = bm * 128, n0 = bn * 128;
    int t = threadIdx.x, lane = t & 63, wv = t >> 6;
    int wr = wv >> 1, wc = wv & 1;
    f32x4 acc[4][4];
#pragma unroll
    for (int i = 0; i < 4; ++i)
#pragma unroll
        for (int j = 0; j < 4; ++j) acc[i][j] = (f32x4)(0.0f);
    int arow = t >> 2, acol = (t & 3) * 8;
    const float* Agf0 = X + (size_t)(m0 + arow) * K_TOTAL + acol;
    const float* Agf1 = Agf0 + (size_t)64 * K_TOTAL;
    const __hip_bfloat16* Bg0 = Wb + (size_t)(n0 + arow) * K_TOTAL + acol;
    const __hip_bfloat16* Bg1 = Bg0 + (size_t)64 * K_TOTAL;
    float4 xa0 = *(const float4*)(Agf0), xa1 = *(const float4*)(Agf0 + 4);
    float4 xb0 = *(const float4*)(Agf1), xb1 = *(const float4*)(Agf1 + 4);
    for (int kt = 0; kt < NT32; ++kt) {
        if (kt) __syncthreads();
        __hip_bfloat162 oa[4] = {
            __float22bfloat162_rn(make_float2(xa0.x, xa0.y)),
            __float22bfloat162_rn(make_float2(xa0.z, xa0.w)),
            __float22bfloat162_rn(make_float2(xa1.x, xa1.y)),
            __float22bfloat162_rn(make_float2(xa1.z, xa1.w))};
        __hip_bfloat162 ob[4] = {
            __float22bfloat162_rn(make_float2(xb0.x, xb0.y)),
            __float22bfloat162_rn(make_float2(xb0.z, xb0.w)),
            __float22bfloat162_rn(make_float2(xb1.x, xb1.y)),
            __float22bfloat162_rn(make_float2(xb1.z, xb1.w))};
        *(int4*)&As[t * 8] = *(int4*)&oa[0];
        *(int4*)&As[2048 + t * 8] = *(int4*)&ob[0];
        gload_lds16(Bg0 + kt * 32, &Bs[t * 8]);
        gload_lds16(Bg1 + kt * 32, &Bs[2048 + t * 8]);
        __syncthreads();
        if (kt < NT32 - 1) {
            int ko = (kt + 1) * 32;
            xa0 = *(const float4*)(Agf0 + ko);
            xa1 = *(const float4*)(Agf0 + ko + 4);
            xb0 = *(const float4*)(Agf1 + ko);
            xb1 = *(const float4*)(Agf1 + ko + 4);
        }
        bf16x8 a[4], b[4];
        int ro = (lane & 15) * 32 + (lane >> 4) * 8;
#pragma unroll
        for (int i = 0; i < 4; ++i)
            a[i] = *(const bf16x8*)&As[(wr * 64 + i * 16) * 32 + ro];
#pragma unroll
        for (int j = 0; j < 4; ++j)
            b[j] = *(const bf16x8*)&Bs[(wc * 64 + j * 16) * 32 + ro];
#pragma unroll
        for (int i = 0; i < 4; ++i)
#pragma unroll
            for (int j = 0; j < 4; ++j)
                acc[i][j] = __builtin_amdgcn_mfma_f32_16x16x32_bf16(a[i], b[j], acc[i][j], 0, 0, 0);
    }
    int col0 = n0 + wc * 64 + (lane & 15);
    int row0 = m0 + wr * 64 + (lane >> 4) * 4;
#pragma unroll
    for (int i = 0; i < 4; ++i)
#pragma unroll
        for (int j = 0; j < 4; ++j) {
            f32x4 v = acc[i][j];
            int r = row0 + i * 16, c = col0 + j * 16;
#pragma unroll
            for (int q = 0; q < 4; ++q)
                out[(size_t)(r + q) * N_TOTAL + c] = v[q];
        }
}

extern "C" void kernel_launch(void* const* d_in, const int* in_sizes, int n_in,
                              void* d_out, int out_size, void* d_ws, size_t ws_size,
                              hipStream_t stream) {
    const float* X = (const float*)d_in[0];
    const int* PW = (const int*)d_in[1];
    const float* SC = (const float*)d_in[2];
    float* OUT = (float*)d_out;

    const size_t needW = (size_t)N_TOTAL * K_TOTAL * 2;            // 33.5 MB
    const size_t needX = needW + (size_t)M_TOTAL * K_TOTAL * 2;    // +134 MB

    if (ws_size >= needX) {
        __hip_bfloat16* Wb = (__hip_bfloat16*)d_ws;
        __hip_bfloat16* Xb = (__hip_bfloat16*)((char*)d_ws + needW);
        k_convX<<<dim3(32768), dim3(256), 0, stream>>>(X, Xb);
        k_dequant<<<dim3(4096), dim3(256), 0, stream>>>(PW, SC, Wb);
        k_gemm18<<<dim3((M_TOTAL / 256) * (N_TOTAL / 256)), dim3(512), 0, stream>>>(Xb, Wb, OUT);
    } else if (ws_size >= needW) {
        __hip_bfloat16* Wb = (__hip_bfloat16*)d_ws;
        k_dequant<<<dim3(4096), dim3(256), 0, stream>>>(PW, SC, Wb);
        k_gemm2b<<<dim3((M_TOTAL / 128) * (N_TOTAL / 128)), dim3(256), 0, stream>>>(X, Wb, OUT);
    }
}